// Round 1
// baseline (1002.983 us; speedup 1.0000x reference)
//
#include <hip/hip_runtime.h>
#include <hip/hip_bf16.h>
#include <stdint.h>

typedef unsigned short u16;
typedef __attribute__((ext_vector_type(8))) short short8;
typedef __attribute__((ext_vector_type(4))) float floatx4;

#define BM 128
#define BN 128
#define BK 64

__device__ __forceinline__ u16 f32_to_bf16(float f) {
  uint32_t u = __float_as_uint(f);
  u += 0x7FFFu + ((u >> 16) & 1u);   // round-to-nearest-even (finite inputs)
  return (u16)(u >> 16);
}
__device__ __forceinline__ float bf16_to_f32(u16 h) {
  return __uint_as_float(((uint32_t)h) << 16);
}
__device__ __forceinline__ float tanh_fast(float x) {
  float xc = fminf(fmaxf(x, -12.f), 12.f);
  float e = __expf(2.0f * xc);
  return 1.0f - __fdividef(2.0f, e + 1.0f);
}

__device__ __forceinline__ void gload_lds16(const void* g, void* l) {
  __builtin_amdgcn_global_load_lds((const __attribute__((address_space(1))) void*)g,
                                   (__attribute__((address_space(3))) void*)l, 16, 0, 0);
}

// stage a BM(=128) x BK(=64) bf16 tile from row-major global (ld elements) into
// linear LDS. gbase points at (row0, k0). 256 threads / 4 waves; LDS dest is
// wave-uniform base + lane*16 (global_load_lds semantics).
__device__ __forceinline__ void stage_tile(const u16* __restrict__ gbase, int ld,
                                           u16* lds, int wave, int lane) {
#pragma unroll
  for (int p = 0; p < 4; ++p) {
    int e = ((p * 4 + wave) * 64 + lane) * 8; // element offset in tile
    int r = e >> 6;                           // /64 (BK)
    int c = e & 63;
    const u16* gp = gbase + (long)r * ld + c;
    u16* lp = lds + (p * 4 + wave) * 512;     // wave-uniform, 1024B per wave-pass
    gload_lds16(gp, lp);
  }
}

// C[M,N] = X[M,K1] @ W[N,K1]^T  (+ X2[M,K2] @ W2[N,K2]^T for MODE 2)
// MODE 0: obf0 = bf16(acc); obf1 = bf16(tanh(acc))          [Bu kernel]
// MODE 1: obf0 = bf16(tanh(acc + bias))                     [iteration]
// MODE 2: of32 = acc (two K segments)                       [final y]
template <int MODE>
__launch_bounds__(256)
__global__ void gemm_bt_kernel(const u16* __restrict__ X, const u16* __restrict__ W, int K1,
                               const u16* __restrict__ X2, const u16* __restrict__ W2, int K2,
                               const u16* __restrict__ bias,
                               u16* __restrict__ obf0, u16* __restrict__ obf1,
                               float* __restrict__ of32, int N) {
  __shared__ __align__(16) u16 sA[BM * BK];
  __shared__ __align__(16) u16 sB[BN * BK];

  const int tid = threadIdx.x;
  const int wave = tid >> 6, lane = tid & 63;
  const int wm = wave >> 1, wn = wave & 1;
  const int fr = lane & 15, fq = lane >> 4;
  const int m0 = blockIdx.x * BM;
  const int n0 = blockIdx.y * BN;

  floatx4 acc[4][4] = {};

  auto compute_tile = [&]() {
#pragma unroll
    for (int kk = 0; kk < 2; ++kk) {
      short8 a[4], b[4];
#pragma unroll
      for (int i = 0; i < 4; ++i) {
        a[i] = *(const short8*)&sA[(wm * 64 + i * 16 + fr) * BK + kk * 32 + fq * 8];
        b[i] = *(const short8*)&sB[(wn * 64 + i * 16 + fr) * BK + kk * 32 + fq * 8];
      }
#pragma unroll
      for (int i = 0; i < 4; ++i)
#pragma unroll
        for (int j = 0; j < 4; ++j)
          acc[i][j] = __builtin_amdgcn_mfma_f32_16x16x32_bf16(a[i], b[j], acc[i][j], 0, 0, 0);
    }
  };

  for (int k0 = 0; k0 < K1; k0 += BK) {
    stage_tile(X + (long)m0 * K1 + k0, K1, sA, wave, lane);
    stage_tile(W + (long)n0 * K1 + k0, K1, sB, wave, lane);
    __syncthreads();   // compiler drains vmcnt before s_barrier
    compute_tile();
    __syncthreads();
  }
  if (MODE == 2) {
    for (int k0 = 0; k0 < K2; k0 += BK) {
      stage_tile(X2 + (long)m0 * K2 + k0, K2, sA, wave, lane);
      stage_tile(W2 + (long)n0 * K2 + k0, K2, sB, wave, lane);
      __syncthreads();
      compute_tile();
      __syncthreads();
    }
  }

  // epilogue: D frag layout col=lane&15, row=(lane>>4)*4+q  [m89/m91 verified]
#pragma unroll
  for (int i = 0; i < 4; ++i) {
#pragma unroll
    for (int j = 0; j < 4; ++j) {
#pragma unroll
      for (int q = 0; q < 4; ++q) {
        int r = m0 + wm * 64 + i * 16 + fq * 4 + q;
        int c = n0 + wn * 64 + j * 16 + fr;
        long idx = (long)r * N + c;
        float v = acc[i][j][q];
        if (MODE == 0) {
          obf0[idx] = f32_to_bf16(v);
          obf1[idx] = f32_to_bf16(tanh_fast(v));
        } else if (MODE == 1) {
          obf0[idx] = f32_to_bf16(tanh_fast(v + bf16_to_f32(bias[idx])));
        } else {
          of32[idx] = v;
        }
      }
    }
  }
}

__global__ void convert_obs_kernel(const float* __restrict__ src, u16* __restrict__ dst) {
  int i = (blockIdx.x * 256 + threadIdx.x) * 4;
  float4 v = *(const float4*)(src + i);
  ushort4 o;
  o.x = f32_to_bf16(v.x);
  o.y = f32_to_bf16(v.y);
  o.z = f32_to_bf16(v.z);
  o.w = f32_to_bf16(v.w);
  *(ushort4*)(dst + i) = o;
}

// src[R][C] f32  ->  dst[C][R] bf16   (weights pre-transposed to [N][K])
__global__ void transpose_convert_kernel(const float* __restrict__ src, u16* __restrict__ dst,
                                         int R, int C) {
  __shared__ float tile[32][33];
  int bx = blockIdx.x * 32;  // col block of src
  int by = blockIdx.y * 32;  // row block of src
  int tx = threadIdx.x & 31, ty = threadIdx.x >> 5;  // 32x8
#pragma unroll
  for (int i = ty; i < 32; i += 8)
    tile[i][tx] = src[(long)(by + i) * C + bx + tx];
  __syncthreads();
#pragma unroll
  for (int i = ty; i < 32; i += 8)
    dst[(long)(bx + i) * R + by + tx] = f32_to_bf16(tile[tx][i]);
}

extern "C" void kernel_launch(void* const* d_in, const int* in_sizes, int n_in,
                              void* d_out, int out_size, void* d_ws, size_t ws_size,
                              hipStream_t stream) {
  const float* obs = (const float*)d_in[0];
  const float* A_T = (const float*)d_in[1];
  const float* B_T = (const float*)d_in[2];
  const float* C_T = (const float*)d_in[3];
  const float* D_T = (const float*)d_in[4];
  float* out = (float*)d_out;

  const int M = 8192, IN = 512, S = 1024, OUT = 512;

  char* ws = (char*)d_ws;
  u16* obs_bf = (u16*)(ws);                  // 8 MB   [M][IN]
  u16* Aw = (u16*)(ws + (8ul << 20));        // 2 MB   [S][S]    Aw[n][k] = A_T[k][n]
  u16* Bw = (u16*)(ws + (10ul << 20));       // 1 MB   [S][IN]   Bw[n][k] = B_T[k][n]
  u16* Cw = (u16*)(ws + (11ul << 20));       // 1 MB   [OUT][S]
  u16* Dw = (u16*)(ws + (12ul << 20));       // 0.5 MB [OUT][IN]
  u16* bu = (u16*)(ws + (13ul << 20));       // 16 MB  [M][S]
  u16* xa = (u16*)(ws + (29ul << 20));       // 16 MB  [M][S]
  u16* xb = (u16*)(ws + (45ul << 20));       // 16 MB  [M][S]  (total 61 MB)

  convert_obs_kernel<<<(M * IN) / 1024, 256, 0, stream>>>(obs, obs_bf);
  transpose_convert_kernel<<<dim3(S / 32, S / 32), 256, 0, stream>>>(A_T, Aw, S, S);
  transpose_convert_kernel<<<dim3(S / 32, IN / 32), 256, 0, stream>>>(B_T, Bw, IN, S);
  transpose_convert_kernel<<<dim3(OUT / 32, S / 32), 256, 0, stream>>>(C_T, Cw, S, OUT);
  transpose_convert_kernel<<<dim3(OUT / 32, IN / 32), 256, 0, stream>>>(D_T, Dw, IN, OUT);

  // Bu = obs @ B_T ; xa = tanh(Bu)  (iteration 1 of 30, since x0 = 0)
  gemm_bt_kernel<0><<<dim3(M / BM, S / BN), 256, 0, stream>>>(
      obs_bf, Bw, IN, nullptr, nullptr, 0, nullptr, bu, xa, nullptr, S);

  // iterations 2..30
  u16* xi = xa;
  u16* xo = xb;
  for (int it = 0; it < 29; ++it) {
    gemm_bt_kernel<1><<<dim3(M / BM, S / BN), 256, 0, stream>>>(
        xi, Aw, S, nullptr, nullptr, 0, bu, xo, nullptr, nullptr, S);
    u16* t = xi; xi = xo; xo = t;
  }

  // y = x @ C_T + obs @ D_T
  gemm_bt_kernel<2><<<dim3(M / BM, OUT / BN), 256, 0, stream>>>(
      xi, Cw, S, obs_bf, Dw, IN, nullptr, nullptr, nullptr, out, OUT);
}

// Round 2
// 772.638 us; speedup vs baseline: 1.2981x; 1.2981x over previous
//
#include <hip/hip_runtime.h>
#include <hip/hip_bf16.h>
#include <stdint.h>

typedef unsigned short u16;
typedef __attribute__((ext_vector_type(8))) short short8;
typedef __attribute__((ext_vector_type(4))) float floatx4;

#define BM 128
#define BN 128
#define BK 64
#define NTHREADS 512

__device__ __forceinline__ u16 f32_to_bf16(float f) {
  uint32_t u = __float_as_uint(f);
  u += 0x7FFFu + ((u >> 16) & 1u);   // round-to-nearest-even (finite inputs)
  return (u16)(u >> 16);
}
__device__ __forceinline__ float bf16_to_f32(u16 h) {
  return __uint_as_float(((uint32_t)h) << 16);
}
__device__ __forceinline__ float tanh_fast(float x) {
  float xc = fminf(fmaxf(x, -12.f), 12.f);
  float e = __expf(2.0f * xc);
  return 1.0f - __fdividef(2.0f, e + 1.0f);
}

__device__ __forceinline__ void gload_lds16(const void* g, void* l) {
  __builtin_amdgcn_global_load_lds((const __attribute__((address_space(1))) void*)g,
                                   (__attribute__((address_space(3))) void*)l, 16, 0, 0);
}

// Stage one BMxBK (=BNxBK) bf16 tile into LDS with XOR-swizzle.
// LDS dest is LINEAR (global_load_lds: wave-uniform base + lane*16);
// the swizzle is applied by permuting the GLOBAL source granule (rule #21):
// stored granule g (row r = g/8, col-granule g&7) holds logical col-granule
// (g&7)^(r&7). Readers XOR the same way -> involution.
__device__ __forceinline__ void stage_tile_swz(const u16* __restrict__ gsrc, int ld,
                                               u16* lds, int tid) {
#pragma unroll
  for (int p = 0; p < 2; ++p) {
    int g = p * NTHREADS + tid;        // granule index, 1024 granules of 16B
    int r = g >> 3;
    int cg = (g & 7) ^ (r & 7);
    gload_lds16(gsrc + (long)r * ld + cg * 8, lds + g * 8);
  }
}

// C[M,N] = X[M,K1] @ W[N,K1]^T  (+ X2[M,K2] @ W2[N,K2]^T for MODE 2)
// MODE 0: obf0 = bf16(acc); obf1 = bf16(tanh(acc))          [Bu kernel]
// MODE 1: obf0 = bf16(tanh(acc + bias))                     [iteration]
// MODE 2: of32 = acc (two K segments)                       [final y]
template <int MODE>
__launch_bounds__(NTHREADS, 4)
__global__ void gemm_bt_kernel(const u16* __restrict__ X, const u16* __restrict__ W, int K1,
                               const u16* __restrict__ X2, const u16* __restrict__ W2, int K2,
                               const u16* __restrict__ bias,
                               u16* __restrict__ obf0, u16* __restrict__ obf1,
                               float* __restrict__ of32, int N) {
  __shared__ __align__(16) u16 sA[2][BM * BK];
  __shared__ __align__(16) u16 sB[2][BN * BK];

  const int tid = threadIdx.x;
  const int wave = tid >> 6, lane = tid & 63;
  const int wm = wave >> 2, wn = wave & 3;      // 2x4 wave grid: 64-row x 32-col
  const int fr = lane & 15, fq = lane >> 4;
  const long m0 = (long)blockIdx.x * BM;
  const long n0 = (long)blockIdx.y * BN;

  const int NT1 = K1 / BK;
  const int NT2 = (MODE == 2) ? K2 / BK : 0;
  const int NT = NT1 + NT2;

  floatx4 acc[4][2] = {};

  auto stage = [&](int t, int buf) {
    if (t < NT1) {
      stage_tile_swz(X + m0 * K1 + t * BK, K1, sA[buf], tid);
      stage_tile_swz(W + n0 * K1 + t * BK, K1, sB[buf], tid);
    } else {
      stage_tile_swz(X2 + m0 * K2 + (t - NT1) * BK, K2, sA[buf], tid);
      stage_tile_swz(W2 + n0 * K2 + (t - NT1) * BK, K2, sB[buf], tid);
    }
  };

  auto compute = [&](int buf) {
#pragma unroll
    for (int kk = 0; kk < 2; ++kk) {
      short8 a[4], b[2];
#pragma unroll
      for (int i = 0; i < 4; ++i) {
        int r = wm * 64 + i * 16 + fr;
        a[i] = *(const short8*)&sA[buf][r * BK + ((kk * 32 + fq * 8) ^ ((r & 7) << 3))];
      }
#pragma unroll
      for (int j = 0; j < 2; ++j) {
        int r = wn * 32 + j * 16 + fr;
        b[j] = *(const short8*)&sB[buf][r * BK + ((kk * 32 + fq * 8) ^ ((r & 7) << 3))];
      }
#pragma unroll
      for (int i = 0; i < 4; ++i)
#pragma unroll
        for (int j = 0; j < 2; ++j)
          acc[i][j] = __builtin_amdgcn_mfma_f32_16x16x32_bf16(a[i], b[j], acc[i][j], 0, 0, 0);
    }
  };

  // Pipelined main loop: stage(t+1) issued BEFORE compute(t); the barrier's
  // implicit vmcnt(0)+lgkmcnt(0) drain lands after the MFMAs -> staging
  // latency hides under compute. One barrier per K-step (ds_reads of buf
  // complete before MFMA via lgkm waits, hence before the barrier).
  stage(0, 0);
  __syncthreads();
  int cur = 0;
  for (int t = 0; t < NT; ++t) {
    if (t + 1 < NT) stage(t + 1, cur ^ 1);
    compute(cur);
    __syncthreads();
    cur ^= 1;
  }

  // epilogue: D frag layout col=lane&15, row=(lane>>4)*4+q  [m89/m91 verified]
#pragma unroll
  for (int i = 0; i < 4; ++i) {
#pragma unroll
    for (int j = 0; j < 2; ++j) {
#pragma unroll
      for (int q = 0; q < 4; ++q) {
        long r = m0 + wm * 64 + i * 16 + fq * 4 + q;
        long c = n0 + wn * 32 + j * 16 + fr;
        long idx = r * N + c;
        float v = acc[i][j][q];
        if (MODE == 0) {
          obf0[idx] = f32_to_bf16(v);
          obf1[idx] = f32_to_bf16(tanh_fast(v));
        } else if (MODE == 1) {
          obf0[idx] = f32_to_bf16(tanh_fast(v + bf16_to_f32(bias[idx])));
        } else {
          of32[idx] = v;
        }
      }
    }
  }
}

__global__ void convert_obs_kernel(const float* __restrict__ src, u16* __restrict__ dst) {
  int i = (blockIdx.x * 256 + threadIdx.x) * 4;
  float4 v = *(const float4*)(src + i);
  ushort4 o;
  o.x = f32_to_bf16(v.x);
  o.y = f32_to_bf16(v.y);
  o.z = f32_to_bf16(v.z);
  o.w = f32_to_bf16(v.w);
  *(ushort4*)(dst + i) = o;
}

// src[R][C] f32  ->  dst[C][R] bf16   (weights pre-transposed to [N][K])
__global__ void transpose_convert_kernel(const float* __restrict__ src, u16* __restrict__ dst,
                                         int R, int C) {
  __shared__ float tile[32][33];
  int bx = blockIdx.x * 32;  // col block of src
  int by = blockIdx.y * 32;  // row block of src
  int tx = threadIdx.x & 31, ty = threadIdx.x >> 5;  // 32x8
#pragma unroll
  for (int i = ty; i < 32; i += 8)
    tile[i][tx] = src[(long)(by + i) * C + bx + tx];
  __syncthreads();
#pragma unroll
  for (int i = ty; i < 32; i += 8)
    dst[(long)(bx + i) * R + by + tx] = f32_to_bf16(tile[tx][i]);
}

extern "C" void kernel_launch(void* const* d_in, const int* in_sizes, int n_in,
                              void* d_out, int out_size, void* d_ws, size_t ws_size,
                              hipStream_t stream) {
  const float* obs = (const float*)d_in[0];
  const float* A_T = (const float*)d_in[1];
  const float* B_T = (const float*)d_in[2];
  const float* C_T = (const float*)d_in[3];
  const float* D_T = (const float*)d_in[4];
  float* out = (float*)d_out;

  const int M = 8192, IN = 512, S = 1024, OUT = 512;

  char* ws = (char*)d_ws;
  u16* obs_bf = (u16*)(ws);                  // 8 MB   [M][IN]
  u16* Aw = (u16*)(ws + (8ul << 20));        // 2 MB   [S][S]    Aw[n][k] = A_T[k][n]
  u16* Bw = (u16*)(ws + (10ul << 20));       // 1 MB   [S][IN]
  u16* Cw = (u16*)(ws + (11ul << 20));       // 1 MB   [OUT][S]
  u16* Dw = (u16*)(ws + (12ul << 20));       // 0.5 MB [OUT][IN]
  u16* bu = (u16*)(ws + (13ul << 20));       // 16 MB  [M][S]
  u16* xa = (u16*)(ws + (29ul << 20));       // 16 MB  [M][S]
  u16* xb = (u16*)(ws + (45ul << 20));       // 16 MB  [M][S]  (total 61 MB)

  convert_obs_kernel<<<(M * IN) / 1024, 256, 0, stream>>>(obs, obs_bf);
  transpose_convert_kernel<<<dim3(S / 32, S / 32), 256, 0, stream>>>(A_T, Aw, S, S);
  transpose_convert_kernel<<<dim3(S / 32, IN / 32), 256, 0, stream>>>(B_T, Bw, IN, S);
  transpose_convert_kernel<<<dim3(OUT / 32, S / 32), 256, 0, stream>>>(C_T, Cw, S, OUT);
  transpose_convert_kernel<<<dim3(OUT / 32, IN / 32), 256, 0, stream>>>(D_T, Dw, IN, OUT);

  // Bu = obs @ B_T ; xa = tanh(Bu)  (iteration 1 of 30, since x0 = 0)
  gemm_bt_kernel<0><<<dim3(M / BM, S / BN), NTHREADS, 0, stream>>>(
      obs_bf, Bw, IN, nullptr, nullptr, 0, nullptr, bu, xa, nullptr, S);

  // iterations 2..30
  u16* xi = xa;
  u16* xo = xb;
  for (int it = 0; it < 29; ++it) {
    gemm_bt_kernel<1><<<dim3(M / BM, S / BN), NTHREADS, 0, stream>>>(
        xi, Aw, S, nullptr, nullptr, 0, bu, xo, nullptr, nullptr, S);
    u16* t = xi; xi = xo; xo = t;
  }

  // y = x @ C_T + obs @ D_T
  gemm_bt_kernel<2><<<dim3(M / BM, OUT / BN), NTHREADS, 0, stream>>>(
      xi, Cw, S, obs_bf, Dw, IN, nullptr, nullptr, nullptr, out, OUT);
}